// Round 9
// baseline (55.114 us; speedup 1.0000x reference)
//
#include <hip/hip_runtime.h>
#include <math.h>

#define B_ 4
#define N_ 8192
#define M_ 8192
#define THREADS 256
#define QPT 8          // queries per thread (raised: halves LDS instrs per FLOP)
#define TCH 256        // targets staged in LDS per block (as 128 pairs)
#define NQTOT (B_ * (N_ + M_))   // 65536 min-slots
#define RBLK 256                 // elements per reduce-A block

typedef float v2f __attribute__((ext_vector_type(2)));

// ---------- init: set min-buffer to +inf bits ----------
__global__ void cd_init_kernel(unsigned* __restrict__ p, int n) {
    int i = blockIdx.x * blockDim.x + threadIdx.x;
    if (i < n) p[i] = 0x7F800000u;   // +inf
}

// ---------- main: both directions in one grid, packed-fp32 inner loop ----------
// blockIdx.z in [0, 2*B): dir = z>>2, b = z&3.
// d2(q,t) = c_q + (|t|^2 - 2 q.t); c_q hoisted out of the min.
__global__ __launch_bounds__(THREADS) void cd_min_all(
        const float* __restrict__ xyz1, const float* __restrict__ xyz2,
        unsigned* __restrict__ mins) {
    __shared__ float4 tA[TCH / 2];   // {x0, x1, y0, y1} per target-pair
    __shared__ float4 tB[TCH / 2];   // {z0, z1, |t0|^2, |t1|^2}

    const int z   = blockIdx.z;
    const int dir = z >> 2;           // 0: q=xyz1,t=xyz2 ; 1: q=xyz2,t=xyz1
    const int b   = z & 3;
    const float* Q = dir ? xyz2 : xyz1;
    const float* T = dir ? xyz1 : xyz2;
    const int nq = dir ? M_ : N_;
    const int nt = dir ? N_ : M_;
    unsigned* ob = mins + (dir ? (size_t)B_ * N_ : 0) + (size_t)b * nq;

    const float* Qb = Q + (size_t)b * nq * 3;
    const float* Tb = T + (size_t)b * nt * 3 + (size_t)blockIdx.y * TCH * 3;

    float m2x[QPT], m2y[QPT], m2z[QPT], c[QPT], dmin[QPT];
    const int qbase = blockIdx.x * (THREADS * QPT) + threadIdx.x;

#pragma unroll
    for (int k = 0; k < QPT; ++k) {
        int q = qbase + k * THREADS;
        float x = Qb[q * 3 + 0], y = Qb[q * 3 + 1], z2 = Qb[q * 3 + 2];
        m2x[k] = -2.0f * x; m2y[k] = -2.0f * y; m2z[k] = -2.0f * z2;
        c[k] = x * x + y * y + z2 * z2;
        dmin[k] = INFINITY;
    }

    // stage target pairs: (TCH/2 == 128) < THREADS, single pass
    for (int p = threadIdx.x; p < TCH / 2; p += THREADS) {
        const float* t0 = Tb + 6 * p;
        float x0 = t0[0], y0 = t0[1], z0 = t0[2];
        float x1 = t0[3], y1 = t0[4], z1 = t0[5];
        tA[p] = make_float4(x0, x1, y0, y1);
        tB[p] = make_float4(z0, z1,
                            x0 * x0 + y0 * y0 + z0 * z0,
                            x1 * x1 + y1 * y1 + z1 * z1);
    }
    __syncthreads();

#pragma unroll 4
    for (int p = 0; p < TCH / 2; ++p) {
        float4 a = tA[p];               // uniform address -> LDS broadcast
        float4 bb = tB[p];
        v2f x2 = (v2f){a.x, a.y};
        v2f y2 = (v2f){a.z, a.w};
        v2f z2 = (v2f){bb.x, bb.y};
        v2f w2 = (v2f){bb.z, bb.w};
#pragma unroll
        for (int k = 0; k < QPT; ++k) {
            v2f d = m2x[k] * x2 + w2;   // -> v_pk_fma_f32
            d = m2y[k] * y2 + d;
            d = m2z[k] * z2 + d;
            dmin[k] = fminf(fminf(dmin[k], d.x), d.y);   // -> v_min3_f32
        }
    }

#pragma unroll
    for (int k = 0; k < QPT; ++k) {
        int q = qbase + k * THREADS;
        float v = fmaxf(c[k] + dmin[k], 0.0f);       // >=0 -> uint order == float order
        atomicMin(&ob[q], __float_as_uint(v));
    }
}

// ---------- reduce stage A: 256 blocks x 256 elements -> partial sums ----------
__global__ __launch_bounds__(RBLK) void cd_reduceA(
        const unsigned* __restrict__ mins, float* __restrict__ partials) {
    __shared__ float sdata[RBLK];
    const int tid = threadIdx.x;
    const int i = blockIdx.x * RBLK + tid;
    float v = sqrtf(__uint_as_float(mins[i]));
    float scale = (i < B_ * N_) ? (1.0f / (float)(B_ * N_)) : (1.0f / (float)(B_ * M_));
    sdata[tid] = v * scale;
    __syncthreads();
    for (int off = RBLK / 2; off > 0; off >>= 1) {
        if (tid < off) sdata[tid] += sdata[tid + off];
        __syncthreads();
    }
    if (tid == 0) partials[blockIdx.x] = sdata[0];
}

// ---------- reduce stage B: 1 block sums the 256 partials ----------
__global__ __launch_bounds__(RBLK) void cd_reduceB(
        const float* __restrict__ partials, float* __restrict__ out) {
    __shared__ float sdata[RBLK];
    const int tid = threadIdx.x;
    sdata[tid] = partials[tid];
    __syncthreads();
    for (int off = RBLK / 2; off > 0; off >>= 1) {
        if (tid < off) sdata[tid] += sdata[tid + off];
        __syncthreads();
    }
    if (tid == 0) out[0] = sdata[0];
}

// ---------- fallback (tiny ws): full target loop per block + atomicAdd ----------
__global__ void cd_zero_out(float* out) { if (threadIdx.x == 0) out[0] = 0.0f; }

__global__ __launch_bounds__(THREADS) void cd_full_kernel(
        const float* __restrict__ Q, const float* __restrict__ T,
        float* __restrict__ out, int nq, int nt, float scale) {
    __shared__ float4 tile[TCH];
    __shared__ float sdata[THREADS];

    const int b = blockIdx.y;
    const float* Qb = Q + (size_t)b * nq * 3;
    const float* Tbase = T + (size_t)b * nt * 3;

    float m2x[QPT], m2y[QPT], m2z[QPT], c[QPT], dmin[QPT];
    const int qbase = blockIdx.x * (THREADS * QPT) + threadIdx.x;
#pragma unroll
    for (int k = 0; k < QPT; ++k) {
        int q = qbase + k * THREADS;
        float x = Qb[q * 3 + 0], y = Qb[q * 3 + 1], z = Qb[q * 3 + 2];
        m2x[k] = -2.0f * x; m2y[k] = -2.0f * y; m2z[k] = -2.0f * z;
        c[k] = x * x + y * y + z * z;
        dmin[k] = INFINITY;
    }

    for (int t0 = 0; t0 < nt; t0 += TCH) {
        __syncthreads();
        for (int j = threadIdx.x; j < TCH; j += THREADS) {
            const float* Tb = Tbase + (size_t)(t0 + j) * 3;
            float x = Tb[0], y = Tb[1], z = Tb[2];
            tile[j] = make_float4(x, y, z, x * x + y * y + z * z);
        }
        __syncthreads();
#pragma unroll 4
        for (int j = 0; j < TCH; ++j) {
            float4 t = tile[j];
#pragma unroll
            for (int k = 0; k < QPT; ++k) {
                float d = fmaf(m2x[k], t.x, t.w);
                d = fmaf(m2y[k], t.y, d);
                d = fmaf(m2z[k], t.z, d);
                dmin[k] = fminf(dmin[k], d);
            }
        }
    }

    float s = 0.0f;
#pragma unroll
    for (int k = 0; k < QPT; ++k) s += sqrtf(fmaxf(c[k] + dmin[k], 0.0f));
    sdata[threadIdx.x] = s;
    __syncthreads();
    for (int off = THREADS / 2; off > 0; off >>= 1) {
        if (threadIdx.x < off) sdata[threadIdx.x] += sdata[threadIdx.x + off];
        __syncthreads();
    }
    if (threadIdx.x == 0) atomicAdd(out, sdata[0] * scale);
}

extern "C" void kernel_launch(void* const* d_in, const int* in_sizes, int n_in,
                              void* d_out, int out_size, void* d_ws, size_t ws_size,
                              hipStream_t stream) {
    const float* xyz1 = (const float*)d_in[0];
    const float* xyz2 = (const float*)d_in[1];
    float* out = (float*)d_out;

    const size_t need = (size_t)NQTOT * sizeof(unsigned) + (NQTOT / RBLK) * sizeof(float);
    if (ws_size >= need) {
        unsigned* mins = (unsigned*)d_ws;
        float* partials = (float*)((char*)d_ws + (size_t)NQTOT * sizeof(unsigned));

        cd_init_kernel<<<NQTOT / 256, 256, 0, stream>>>(mins, NQTOT);

        // merged grid: x=qchunks(4), y=tchunks(32), z=dir*B+b(8) -> 1024 blocks
        dim3 g(N_ / (THREADS * QPT), M_ / TCH, 2 * B_);
        cd_min_all<<<g, THREADS, 0, stream>>>(xyz1, xyz2, mins);

        cd_reduceA<<<NQTOT / RBLK, RBLK, 0, stream>>>(mins, partials);
        cd_reduceB<<<1, RBLK, 0, stream>>>(partials, out);
    } else {
        cd_zero_out<<<1, 64, 0, stream>>>(out);
        dim3 g1(N_ / (THREADS * QPT), B_);
        cd_full_kernel<<<g1, THREADS, 0, stream>>>(xyz1, xyz2, out, N_, M_,
                                                   1.0f / (float)(B_ * N_));
        dim3 g2(M_ / (THREADS * QPT), B_);
        cd_full_kernel<<<g2, THREADS, 0, stream>>>(xyz2, xyz1, out, M_, N_,
                                                   1.0f / (float)(B_ * M_));
    }
}

// Round 10
// 54.561 us; speedup vs baseline: 1.0101x; 1.0101x over previous
//
#include <hip/hip_runtime.h>
#include <math.h>

#define B_ 4
#define N_ 8192
#define M_ 8192
#define THREADS 256     // 4 waves per block
#define QB 128          // query rows per block (4 waves x 32)
#define TC 512          // targets per LDS chunk
#define NQTOT (B_ * (N_ + M_))   // 65536 min-slots
#define RBLK 256

typedef __attribute__((ext_vector_type(8)))  short bf16x8;   // 8 bf16 = 4 VGPR
typedef __attribute__((ext_vector_type(16))) float f32x16;   // MFMA 32x32 acc

__device__ __forceinline__ unsigned short rne_bf16(float f) {
    unsigned u = __float_as_uint(f);
    return (unsigned short)((u + 0x7FFFu + ((u >> 16) & 1u)) >> 16);
}
__device__ __forceinline__ float bf16_up(unsigned short h) {
    return __uint_as_float(((unsigned)h) << 16);
}
__device__ __forceinline__ void split2(float v, short& hi, short& lo) {
    unsigned short h = rne_bf16(v);
    hi = (short)h;
    lo = (short)rne_bf16(v - bf16_up(h));
}

// ---------- init: +inf bits ----------
__global__ void cd_init_kernel(unsigned* __restrict__ p, int n) {
    int i = blockIdx.x * blockDim.x + threadIdx.x;
    if (i < n) p[i] = 0x7F800000u;
}

// ---------- MFMA chamfer: one pass computes D=d^2 tiles; row-min -> min1 (direct
// store, unique owner), col-min -> LDS ds_min -> global atomicMin (min2). ----------
__global__ __launch_bounds__(THREADS) void cd_mfma(
        const float* __restrict__ xyz1, const float* __restrict__ xyz2,
        unsigned* __restrict__ gmin1, unsigned* __restrict__ gmin2) {
    __shared__ short    sB[TC * 16];     // [tile16][half2][col32][j8] bf16 B-frags, 16KB
    __shared__ unsigned sCol[M_];        // running col-min (d^2 bits), 32KB

    const int b    = blockIdx.y;
    const int tid  = threadIdx.x;
    const int lane = tid & 63;
    const int wave = tid >> 6;
    const float* P1 = xyz1 + (size_t)b * N_ * 3;
    const float* P2 = xyz2 + (size_t)b * M_ * 3;

    for (int i = tid; i < M_; i += THREADS) sCol[i] = 0x7F800000u;

    // ---- A fragment: row = lane&31 (query), k-half = lane>>5, built once ----
    const int qrow = blockIdx.x * QB + wave * 32 + (lane & 31);
    const float qx = P1[qrow * 3 + 0], qy = P1[qrow * 3 + 1], qz = P1[qrow * 3 + 2];
    short hax, lax, hay, lay, haz, laz, hP, lP;
    split2(-2.0f * qx, hax, lax);
    split2(-2.0f * qy, hay, lay);
    split2(-2.0f * qz, haz, laz);
    const float Pq = fmaf(qx, qx, fmaf(qy, qy, qz * qz));
    split2(Pq, hP, lP);
    const short ONE = (short)0x3F80;     // bf16(1.0)
    bf16x8 afrag;
    if (lane < 32) afrag = (bf16x8){hax, hax, lax, hay, hay, lay, haz, haz}; // k0-7
    else           afrag = (bf16x8){laz, ONE, ONE, hP, lP, 0, 0, 0};         // k8-15

    float rmin[16];
#pragma unroll
    for (int r = 0; r < 16; ++r) rmin[r] = INFINITY;

    const f32x16 zacc = {};

    for (int c0 = 0; c0 < M_; c0 += TC) {
        __syncthreads();                 // protect sB from previous readers
        // ---- stage TC targets as packed B fragments ----
        for (int t = tid; t < TC; t += THREADS) {
            const int g = c0 + t;
            const float gx = P2[g * 3 + 0], gy = P2[g * 3 + 1], gz = P2[g * 3 + 2];
            short hgx, lgx, hgy, lgy, hgz, lgz, hS, lS;
            split2(gx, hgx, lgx);
            split2(gy, hgy, lgy);
            split2(gz, hgz, lgz);
            const float S = fmaf(gx, gx, fmaf(gy, gy, gz * gz));
            split2(S, hS, lS);
            bf16x8 h0 = (bf16x8){hgx, lgx, hgx, hgy, lgy, hgy, hgz, lgz}; // k0-7
            bf16x8 h1 = (bf16x8){hgz, hS, lS, ONE, ONE, 0, 0, 0};         // k8-15
            const int tl = t >> 5, cc = t & 31;
            *(bf16x8*)&sB[((tl * 2 + 0) * 32 + cc) * 8] = h0;
            *(bf16x8*)&sB[((tl * 2 + 1) * 32 + cc) * 8] = h1;
        }
        __syncthreads();

        // ---- 16 tiles of 32 cols; 2-deep to hide MFMA latency ----
        for (int tl = 0; tl < TC / 32; tl += 2) {
            bf16x8 b0 = *(bf16x8*)&sB[((tl + 0) * 64 + lane) * 8];
            bf16x8 b1 = *(bf16x8*)&sB[((tl + 1) * 64 + lane) * 8];
            f32x16 a0 = __builtin_amdgcn_mfma_f32_32x32x16_bf16(afrag, b0, zacc, 0, 0, 0);
            f32x16 a1 = __builtin_amdgcn_mfma_f32_32x32x16_bf16(afrag, b1, zacc, 0, 0, 0);
#pragma unroll
            for (int u = 0; u < 2; ++u) {
                f32x16 ac = u ? a1 : a0;
#pragma unroll
                for (int r = 0; r < 16; ++r) rmin[r] = fminf(rmin[r], ac[r]);
                // col-min over this lane's 16 rows (min3 chain)
                float m = fminf(fminf(ac[0], ac[1]), ac[2]);
                m = fminf(fminf(m, ac[3]),  ac[4]);
                m = fminf(fminf(m, ac[5]),  ac[6]);
                m = fminf(fminf(m, ac[7]),  ac[8]);
                m = fminf(fminf(m, ac[9]),  ac[10]);
                m = fminf(fminf(m, ac[11]), ac[12]);
                m = fminf(fminf(m, ac[13]), ac[14]);
                m = fmaxf(fminf(m, ac[15]), 0.0f);
                // both k-half lane groups ds_min the same col -> full 32-row min
                atomicMin(&sCol[c0 + (tl + u) * 32 + (lane & 31)], __float_as_uint(m));
            }
        }
    }

    // ---- query-min: reduce across the 32 col-lanes, direct store ----
#pragma unroll
    for (int s = 1; s <= 16; s <<= 1) {
#pragma unroll
        for (int r = 0; r < 16; ++r) rmin[r] = fminf(rmin[r], __shfl_xor(rmin[r], s));
    }
    if ((lane & 31) == 0) {
        const int h = lane >> 5;
#pragma unroll
        for (int r = 0; r < 16; ++r) {
            const int row = (r & 3) + 8 * (r >> 2) + 4 * h;   // verified C/D mapping
            gmin1[(size_t)b * N_ + blockIdx.x * QB + wave * 32 + row] =
                __float_as_uint(fmaxf(rmin[r], 0.0f));
        }
    }

    // ---- target-min: merge block-local col-mins to global ----
    __syncthreads();
    for (int i = tid; i < M_; i += THREADS)
        atomicMin(&gmin2[(size_t)b * M_ + i], sCol[i]);
}

// ---------- reduce A: 256 blocks x 256 -> partials (sqrt of d^2 here) ----------
__global__ __launch_bounds__(RBLK) void cd_reduceA(
        const unsigned* __restrict__ mins, float* __restrict__ partials) {
    __shared__ float sdata[RBLK];
    const int tid = threadIdx.x;
    const int i = blockIdx.x * RBLK + tid;
    float v = sqrtf(__uint_as_float(mins[i]));
    float scale = (i < B_ * N_) ? (1.0f / (float)(B_ * N_)) : (1.0f / (float)(B_ * M_));
    sdata[tid] = v * scale;
    __syncthreads();
    for (int off = RBLK / 2; off > 0; off >>= 1) {
        if (tid < off) sdata[tid] += sdata[tid + off];
        __syncthreads();
    }
    if (tid == 0) partials[blockIdx.x] = sdata[0];
}

__global__ __launch_bounds__(RBLK) void cd_reduceB(
        const float* __restrict__ partials, float* __restrict__ out) {
    __shared__ float sdata[RBLK];
    const int tid = threadIdx.x;
    sdata[tid] = partials[tid];
    __syncthreads();
    for (int off = RBLK / 2; off > 0; off >>= 1) {
        if (tid < off) sdata[tid] += sdata[tid + off];
        __syncthreads();
    }
    if (tid == 0) out[0] = sdata[0];
}

// ---------- fallback (tiny ws): scalar full-loop + atomicAdd ----------
#define FQPT 8
#define FTCH 256
__global__ void cd_zero_out(float* out) { if (threadIdx.x == 0) out[0] = 0.0f; }

__global__ __launch_bounds__(THREADS) void cd_full_kernel(
        const float* __restrict__ Q, const float* __restrict__ T,
        float* __restrict__ out, int nq, int nt, float scale) {
    __shared__ float4 tile[FTCH];
    __shared__ float sdata[THREADS];
    const int b = blockIdx.y;
    const float* Qb = Q + (size_t)b * nq * 3;
    const float* Tbase = T + (size_t)b * nt * 3;
    float m2x[FQPT], m2y[FQPT], m2z[FQPT], c[FQPT], dmin[FQPT];
    const int qbase = blockIdx.x * (THREADS * FQPT) + threadIdx.x;
#pragma unroll
    for (int k = 0; k < FQPT; ++k) {
        int q = qbase + k * THREADS;
        float x = Qb[q * 3 + 0], y = Qb[q * 3 + 1], z = Qb[q * 3 + 2];
        m2x[k] = -2.0f * x; m2y[k] = -2.0f * y; m2z[k] = -2.0f * z;
        c[k] = x * x + y * y + z * z;
        dmin[k] = INFINITY;
    }
    for (int t0 = 0; t0 < nt; t0 += FTCH) {
        __syncthreads();
        for (int j = threadIdx.x; j < FTCH; j += THREADS) {
            const float* Tb = Tbase + (size_t)(t0 + j) * 3;
            float x = Tb[0], y = Tb[1], z = Tb[2];
            tile[j] = make_float4(x, y, z, x * x + y * y + z * z);
        }
        __syncthreads();
#pragma unroll 4
        for (int j = 0; j < FTCH; ++j) {
            float4 t = tile[j];
#pragma unroll
            for (int k = 0; k < FQPT; ++k) {
                float d = fmaf(m2x[k], t.x, t.w);
                d = fmaf(m2y[k], t.y, d);
                d = fmaf(m2z[k], t.z, d);
                dmin[k] = fminf(dmin[k], d);
            }
        }
    }
    float s = 0.0f;
#pragma unroll
    for (int k = 0; k < FQPT; ++k) s += sqrtf(fmaxf(c[k] + dmin[k], 0.0f));
    sdata[threadIdx.x] = s;
    __syncthreads();
    for (int off = THREADS / 2; off > 0; off >>= 1) {
        if (threadIdx.x < off) sdata[threadIdx.x] += sdata[threadIdx.x + off];
        __syncthreads();
    }
    if (threadIdx.x == 0) atomicAdd(out, sdata[0] * scale);
}

extern "C" void kernel_launch(void* const* d_in, const int* in_sizes, int n_in,
                              void* d_out, int out_size, void* d_ws, size_t ws_size,
                              hipStream_t stream) {
    const float* xyz1 = (const float*)d_in[0];
    const float* xyz2 = (const float*)d_in[1];
    float* out = (float*)d_out;

    const size_t need = (size_t)NQTOT * sizeof(unsigned) + (NQTOT / RBLK) * sizeof(float);
    if (ws_size >= need) {
        unsigned* mins = (unsigned*)d_ws;
        float* partials = (float*)((char*)d_ws + (size_t)NQTOT * sizeof(unsigned));

        cd_init_kernel<<<NQTOT / 256, 256, 0, stream>>>(mins, NQTOT);

        dim3 g(N_ / QB, B_);   // (64, 4) = 256 blocks, 1 per CU
        cd_mfma<<<g, THREADS, 0, stream>>>(xyz1, xyz2, mins, mins + (size_t)B_ * N_);

        cd_reduceA<<<NQTOT / RBLK, RBLK, 0, stream>>>(mins, partials);
        cd_reduceB<<<1, RBLK, 0, stream>>>(partials, out);
    } else {
        cd_zero_out<<<1, 64, 0, stream>>>(out);
        dim3 g1(N_ / (THREADS * FQPT), B_);
        cd_full_kernel<<<g1, THREADS, 0, stream>>>(xyz1, xyz2, out, N_, M_,
                                                   1.0f / (float)(B_ * N_));
        dim3 g2(M_ / (THREADS * FQPT), B_);
        cd_full_kernel<<<g2, THREADS, 0, stream>>>(xyz2, xyz1, out, M_, N_,
                                                   1.0f / (float)(B_ * M_));
    }
}

// Round 11
// 43.846 us; speedup vs baseline: 1.2570x; 1.2444x over previous
//
#include <hip/hip_runtime.h>
#include <math.h>

#define B_ 4
#define N_ 8192
#define M_ 8192
#define THREADS 256     // 4 waves per block
#define QB 128          // query rows per block (4 waves x 32)
#define MSPLIT 4        // target-dim split across blocks
#define MCH (M_ / MSPLIT)   // 2048 cols per block
#define TC 512          // targets per LDS chunk
#define NQTOT (B_ * (N_ + M_))   // 65536 min-slots
#define RBLK 256

typedef __attribute__((ext_vector_type(8)))  short bf16x8;   // 8 bf16 = 4 VGPR
typedef __attribute__((ext_vector_type(16))) float f32x16;   // MFMA 32x32 acc

__device__ __forceinline__ unsigned short rne_bf16(float f) {
    unsigned u = __float_as_uint(f);
    return (unsigned short)((u + 0x7FFFu + ((u >> 16) & 1u)) >> 16);
}
__device__ __forceinline__ float bf16_up(unsigned short h) {
    return __uint_as_float(((unsigned)h) << 16);
}
__device__ __forceinline__ void split2(float v, short& hi, short& lo) {
    unsigned short h = rne_bf16(v);
    hi = (short)h;
    lo = (short)rne_bf16(v - bf16_up(h));
}

// ---------- init: +inf bits ----------
__global__ void cd_init_kernel(unsigned* __restrict__ p, int n) {
    int i = blockIdx.x * blockDim.x + threadIdx.x;
    if (i < n) p[i] = 0x7F800000u;
}

// ---------- MFMA chamfer, col-split for occupancy ----------
__global__ __launch_bounds__(THREADS) void cd_mfma(
        const float* __restrict__ xyz1, const float* __restrict__ xyz2,
        unsigned* __restrict__ gmin1, unsigned* __restrict__ gmin2) {
    __shared__ short    sB[TC * 16];     // packed bf16 B-frags, 16KB
    __shared__ unsigned sCol[MCH];       // running col-min (d^2 bits), 8KB

    const int b     = blockIdx.y;
    const int mbase = blockIdx.z * MCH;
    const int tid   = threadIdx.x;
    const int lane  = tid & 63;
    const int wave  = tid >> 6;
    const float* P1 = xyz1 + (size_t)b * N_ * 3;
    const float* P2 = xyz2 + (size_t)b * M_ * 3 + (size_t)mbase * 3;

    for (int i = tid; i < MCH; i += THREADS) sCol[i] = 0x7F800000u;

    // ---- A fragment: row = lane&31 (query), k-half = lane>>5, built once ----
    const int qrow = blockIdx.x * QB + wave * 32 + (lane & 31);
    const float qx = P1[qrow * 3 + 0], qy = P1[qrow * 3 + 1], qz = P1[qrow * 3 + 2];
    short hax, lax, hay, lay, haz, laz, hP, lP;
    split2(-2.0f * qx, hax, lax);
    split2(-2.0f * qy, hay, lay);
    split2(-2.0f * qz, haz, laz);
    const float Pq = fmaf(qx, qx, fmaf(qy, qy, qz * qz));
    split2(Pq, hP, lP);
    const short ONE = (short)0x3F80;     // bf16(1.0)
    bf16x8 afrag;
    if (lane < 32) afrag = (bf16x8){hax, hax, lax, hay, hay, lay, haz, haz}; // k0-7
    else           afrag = (bf16x8){laz, ONE, ONE, hP, lP, 0, 0, 0};         // k8-15

    float rmin[16];
#pragma unroll
    for (int r = 0; r < 16; ++r) rmin[r] = INFINITY;

    const f32x16 zacc = {};

    for (int c0 = 0; c0 < MCH; c0 += TC) {
        __syncthreads();                 // protect sB from previous readers
        // ---- stage TC targets as packed B fragments ----
        for (int t = tid; t < TC; t += THREADS) {
            const int g = c0 + t;
            const float gx = P2[g * 3 + 0], gy = P2[g * 3 + 1], gz = P2[g * 3 + 2];
            short hgx, lgx, hgy, lgy, hgz, lgz, hS, lS;
            split2(gx, hgx, lgx);
            split2(gy, hgy, lgy);
            split2(gz, hgz, lgz);
            const float S = fmaf(gx, gx, fmaf(gy, gy, gz * gz));
            split2(S, hS, lS);
            bf16x8 h0 = (bf16x8){hgx, lgx, hgx, hgy, lgy, hgy, hgz, lgz}; // k0-7
            bf16x8 h1 = (bf16x8){hgz, hS, lS, ONE, ONE, 0, 0, 0};         // k8-15
            const int tl = t >> 5, cc = t & 31;
            *(bf16x8*)&sB[((tl * 2 + 0) * 32 + cc) * 8] = h0;
            *(bf16x8*)&sB[((tl * 2 + 1) * 32 + cc) * 8] = h1;
        }
        __syncthreads();

        // ---- 16 tiles of 32 cols; 2-deep to hide MFMA latency ----
        for (int tl = 0; tl < TC / 32; tl += 2) {
            bf16x8 b0 = *(bf16x8*)&sB[((tl + 0) * 64 + lane) * 8];
            bf16x8 b1 = *(bf16x8*)&sB[((tl + 1) * 64 + lane) * 8];
            f32x16 a0 = __builtin_amdgcn_mfma_f32_32x32x16_bf16(afrag, b0, zacc, 0, 0, 0);
            f32x16 a1 = __builtin_amdgcn_mfma_f32_32x32x16_bf16(afrag, b1, zacc, 0, 0, 0);
#pragma unroll
            for (int u = 0; u < 2; ++u) {
                f32x16 ac = u ? a1 : a0;
#pragma unroll
                for (int r = 0; r < 16; ++r) rmin[r] = fminf(rmin[r], ac[r]);
                // col-min over this lane's 16 rows (min3 chain)
                float m = fminf(fminf(ac[0], ac[1]), ac[2]);
                m = fminf(fminf(m, ac[3]),  ac[4]);
                m = fminf(fminf(m, ac[5]),  ac[6]);
                m = fminf(fminf(m, ac[7]),  ac[8]);
                m = fminf(fminf(m, ac[9]),  ac[10]);
                m = fminf(fminf(m, ac[11]), ac[12]);
                m = fminf(fminf(m, ac[13]), ac[14]);
                m = fmaxf(fminf(m, ac[15]), 0.0f);
                // both k-half lane groups ds_min the same col -> full 32-row min
                atomicMin(&sCol[c0 + (tl + u) * 32 + (lane & 31)], __float_as_uint(m));
            }
        }
    }

    // ---- query-min: reduce across the 32 col-lanes; atomicMin (col-split) ----
#pragma unroll
    for (int s = 1; s <= 16; s <<= 1) {
#pragma unroll
        for (int r = 0; r < 16; ++r) rmin[r] = fminf(rmin[r], __shfl_xor(rmin[r], s));
    }
    if ((lane & 31) == 0) {
        const int h = lane >> 5;
#pragma unroll
        for (int r = 0; r < 16; ++r) {
            const int row = (r & 3) + 8 * (r >> 2) + 4 * h;   // verified C/D mapping
            atomicMin(&gmin1[(size_t)b * N_ + blockIdx.x * QB + wave * 32 + row],
                      __float_as_uint(fmaxf(rmin[r], 0.0f)));
        }
    }

    // ---- target-min: merge block-local col-mins to global ----
    __syncthreads();
    for (int i = tid; i < MCH; i += THREADS)
        atomicMin(&gmin2[(size_t)b * M_ + mbase + i], sCol[i]);
}

// ---------- reduce A: 256 blocks x 256 -> partials (sqrt of d^2 here) ----------
__global__ __launch_bounds__(RBLK) void cd_reduceA(
        const unsigned* __restrict__ mins, float* __restrict__ partials) {
    __shared__ float sdata[RBLK];
    const int tid = threadIdx.x;
    const int i = blockIdx.x * RBLK + tid;
    float v = sqrtf(__uint_as_float(mins[i]));
    float scale = (i < B_ * N_) ? (1.0f / (float)(B_ * N_)) : (1.0f / (float)(B_ * M_));
    sdata[tid] = v * scale;
    __syncthreads();
    for (int off = RBLK / 2; off > 0; off >>= 1) {
        if (tid < off) sdata[tid] += sdata[tid + off];
        __syncthreads();
    }
    if (tid == 0) partials[blockIdx.x] = sdata[0];
}

__global__ __launch_bounds__(RBLK) void cd_reduceB(
        const float* __restrict__ partials, float* __restrict__ out) {
    __shared__ float sdata[RBLK];
    const int tid = threadIdx.x;
    sdata[tid] = partials[tid];
    __syncthreads();
    for (int off = RBLK / 2; off > 0; off >>= 1) {
        if (tid < off) sdata[tid] += sdata[tid + off];
        __syncthreads();
    }
    if (tid == 0) out[0] = sdata[0];
}

// ---------- fallback (tiny ws): scalar full-loop + atomicAdd ----------
#define FQPT 8
#define FTCH 256
__global__ void cd_zero_out(float* out) { if (threadIdx.x == 0) out[0] = 0.0f; }

__global__ __launch_bounds__(THREADS) void cd_full_kernel(
        const float* __restrict__ Q, const float* __restrict__ T,
        float* __restrict__ out, int nq, int nt, float scale) {
    __shared__ float4 tile[FTCH];
    __shared__ float sdata[THREADS];
    const int b = blockIdx.y;
    const float* Qb = Q + (size_t)b * nq * 3;
    const float* Tbase = T + (size_t)b * nt * 3;
    float m2x[FQPT], m2y[FQPT], m2z[FQPT], c[FQPT], dmin[FQPT];
    const int qbase = blockIdx.x * (THREADS * FQPT) + threadIdx.x;
#pragma unroll
    for (int k = 0; k < FQPT; ++k) {
        int q = qbase + k * THREADS;
        float x = Qb[q * 3 + 0], y = Qb[q * 3 + 1], z = Qb[q * 3 + 2];
        m2x[k] = -2.0f * x; m2y[k] = -2.0f * y; m2z[k] = -2.0f * z;
        c[k] = x * x + y * y + z * z;
        dmin[k] = INFINITY;
    }
    for (int t0 = 0; t0 < nt; t0 += FTCH) {
        __syncthreads();
        for (int j = threadIdx.x; j < FTCH; j += THREADS) {
            const float* Tb = Tbase + (size_t)(t0 + j) * 3;
            float x = Tb[0], y = Tb[1], z = Tb[2];
            tile[j] = make_float4(x, y, z, x * x + y * y + z * z);
        }
        __syncthreads();
#pragma unroll 4
        for (int j = 0; j < FTCH; ++j) {
            float4 t = tile[j];
#pragma unroll
            for (int k = 0; k < FQPT; ++k) {
                float d = fmaf(m2x[k], t.x, t.w);
                d = fmaf(m2y[k], t.y, d);
                d = fmaf(m2z[k], t.z, d);
                dmin[k] = fminf(dmin[k], d);
            }
        }
    }
    float s = 0.0f;
#pragma unroll
    for (int k = 0; k < FQPT; ++k) s += sqrtf(fmaxf(c[k] + dmin[k], 0.0f));
    sdata[threadIdx.x] = s;
    __syncthreads();
    for (int off = THREADS / 2; off > 0; off >>= 1) {
        if (threadIdx.x < off) sdata[threadIdx.x] += sdata[threadIdx.x + off];
        __syncthreads();
    }
    if (threadIdx.x == 0) atomicAdd(out, sdata[0] * scale);
}

extern "C" void kernel_launch(void* const* d_in, const int* in_sizes, int n_in,
                              void* d_out, int out_size, void* d_ws, size_t ws_size,
                              hipStream_t stream) {
    const float* xyz1 = (const float*)d_in[0];
    const float* xyz2 = (const float*)d_in[1];
    float* out = (float*)d_out;

    const size_t need = (size_t)NQTOT * sizeof(unsigned) + (NQTOT / RBLK) * sizeof(float);
    if (ws_size >= need) {
        unsigned* mins = (unsigned*)d_ws;
        float* partials = (float*)((char*)d_ws + (size_t)NQTOT * sizeof(unsigned));

        cd_init_kernel<<<NQTOT / 256, 256, 0, stream>>>(mins, NQTOT);

        dim3 g(N_ / QB, B_, MSPLIT);   // (64, 4, 4) = 1024 blocks, ~4 per CU
        cd_mfma<<<g, THREADS, 0, stream>>>(xyz1, xyz2, mins, mins + (size_t)B_ * N_);

        cd_reduceA<<<NQTOT / RBLK, RBLK, 0, stream>>>(mins, partials);
        cd_reduceB<<<1, RBLK, 0, stream>>>(partials, out);
    } else {
        cd_zero_out<<<1, 64, 0, stream>>>(out);
        dim3 g1(N_ / (THREADS * FQPT), B_);
        cd_full_kernel<<<g1, THREADS, 0, stream>>>(xyz1, xyz2, out, N_, M_,
                                                   1.0f / (float)(B_ * N_));
        dim3 g2(M_ / (THREADS * FQPT), B_);
        cd_full_kernel<<<g2, THREADS, 0, stream>>>(xyz2, xyz1, out, M_, N_,
                                                   1.0f / (float)(B_ * M_));
    }
}